// Round 8
// baseline (175.461 us; speedup 1.0000x reference)
//
#include <hip/hip_runtime.h>
#include <cmath>

// CNEncoder reduced form (MCMC/graph path cancels; see round-0 derivation):
//   P_i = sum_j nx[i,j]; S_i = sum_j rf[i,j]; scale_i = P_i/(S_i+EPS)
//   t = rf*scale; global tmin/tmax/mean -> affine out = rf*(scale_i*A)+B
//   reg_loss = sum(rf^2)*1e-4
// st = sum_i sc_i*S_i computed as sum_i P_i (rel. err ~7e-12).
//
// r7 post-mortem: fused dual-stream stats pass pins at ~140us across 4
// structures; split single-stream kernels run ~2x faster per byte, and rf
// is L3-resident across replays (k_stats FETCH ~= nx only). This round:
// SPLIT passes, ordered so the previous replay's NT-store drain overlaps
// the L3-only rf-stats pass:
//   k_rfstats (rf from L3) -> k_p (nx HBM, NT) -> k_scalars -> k_finalize
// Steady-state HBM per replay = nx 240MB + out 240MB.

static constexpr int NS = 20000;
static constexpr int NG = 3000;
static constexpr int G4 = NG / 4;        // 750 fv4/row, row stride 12000 B
static constexpr float EPS = 1e-8f;

typedef float fv4 __attribute__((ext_vector_type(4)));

// ws floats: [0,NS) S | [NS,2NS) P | [2NS,3NS) Q | [3NS,4NS) MN | [4NS,5NS) MX | AB[2]

// ---- pass 1: per-row stats of rf (L3-resident), wave per row ----
__global__ __launch_bounds__(256) void k_rfstats(
    const fv4* __restrict__ rf,
    float* __restrict__ S, float* __restrict__ Q,
    float* __restrict__ MN, float* __restrict__ MX)
{
    const int row  = blockIdx.x * 4 + (threadIdx.x >> 6);
    const int lane = threadIdx.x & 63;
    const fv4* r = rf + (size_t)row * G4;
    float s0 = 0.f, s1 = 0.f, q0 = 0.f, q1 = 0.f;
    float mn0 = INFINITY, mn1 = INFINITY, mx0 = -INFINITY, mx1 = -INFINITY;
    #pragma unroll
    for (int i = 0; i < 12; ++i) {
        const int c = lane + i * 64;
        if (c < G4) {
            fv4 a = r[c];
            if (i & 1) {
                s1 += (a.x + a.y) + (a.z + a.w);
                q1 += a.x * a.x + a.y * a.y + a.z * a.z + a.w * a.w;
                mn1 = fminf(mn1, fminf(fminf(a.x, a.y), fminf(a.z, a.w)));
                mx1 = fmaxf(mx1, fmaxf(fmaxf(a.x, a.y), fmaxf(a.z, a.w)));
            } else {
                s0 += (a.x + a.y) + (a.z + a.w);
                q0 += a.x * a.x + a.y * a.y + a.z * a.z + a.w * a.w;
                mn0 = fminf(mn0, fminf(fminf(a.x, a.y), fminf(a.z, a.w)));
                mx0 = fmaxf(mx0, fmaxf(fmaxf(a.x, a.y), fmaxf(a.z, a.w)));
            }
        }
    }
    float s = s0 + s1, q = q0 + q1;
    float mn = fminf(mn0, mn1), mx = fmaxf(mx0, mx1);
    #pragma unroll
    for (int off = 32; off > 0; off >>= 1) {
        s += __shfl_down(s, off);
        q += __shfl_down(q, off);
        mn = fminf(mn, __shfl_down(mn, off));
        mx = fmaxf(mx, __shfl_down(mx, off));
    }
    if (lane == 0) { S[row] = s; Q[row] = q; MN[row] = mn; MX[row] = mx; }
}

// ---- pass 2: per-row sum of nx (HBM stream, NT), wave per row ----
__global__ __launch_bounds__(256) void k_p(const fv4* __restrict__ nx,
                                           float* __restrict__ P)
{
    const int row  = blockIdx.x * 4 + (threadIdx.x >> 6);
    const int lane = threadIdx.x & 63;
    const fv4* n = nx + (size_t)row * G4;
    float p0 = 0.f, p1 = 0.f;
    #pragma unroll
    for (int i = 0; i < 12; ++i) {
        const int c = lane + i * 64;
        if (c < G4) {
            fv4 b = __builtin_nontemporal_load(n + c);
            if (i & 1) p1 += (b.x + b.y) + (b.z + b.w);
            else       p0 += (b.x + b.y) + (b.z + b.w);
        }
    }
    float p = p0 + p1;
    #pragma unroll
    for (int off = 32; off > 0; off >>= 1) p += __shfl_down(p, off);
    if (lane == 0) P[row] = p;
}

// ---- pass 3: fold per-row stats into {A,B} and reg_loss ----
__global__ __launch_bounds__(256) void k_scalars(
    const float* __restrict__ S, const float* __restrict__ P,
    const float* __restrict__ Q,
    const float* __restrict__ MN, const float* __restrict__ MX,
    float* __restrict__ AB, float* __restrict__ loss_out)
{
    double st = 0.0, sq = 0.0;
    float tmn = INFINITY, tmx = -INFINITY;
    for (int i = threadIdx.x; i < NS; i += 256) {
        const float s = S[i], p = P[i];
        const float sc = p / (s + EPS);
        st += (double)p;
        sq += (double)Q[i];
        tmn = fminf(tmn, MN[i] * sc);
        tmx = fmaxf(tmx, MX[i] * sc);
    }
    #pragma unroll
    for (int off = 32; off > 0; off >>= 1) {
        st += __shfl_down(st, off);
        sq += __shfl_down(sq, off);
        tmn = fminf(tmn, __shfl_down(tmn, off));
        tmx = fmaxf(tmx, __shfl_down(tmx, off));
    }
    __shared__ double lst[4], lsq[4];
    __shared__ float lmn[4], lmx[4];
    const int wid = threadIdx.x >> 6;
    if ((threadIdx.x & 63) == 0) { lst[wid] = st; lsq[wid] = sq; lmn[wid] = tmn; lmx[wid] = tmx; }
    __syncthreads();
    if (threadIdx.x == 0) {
        st  = (lst[0] + lst[1]) + (lst[2] + lst[3]);
        sq  = (lsq[0] + lsq[1]) + (lsq[2] + lsq[3]);
        tmn = fminf(fminf(lmn[0], lmn[1]), fminf(lmn[2], lmn[3]));
        tmx = fmaxf(fmaxf(lmx[0], lmx[1]), fmaxf(lmx[2], lmx[3]));
        const float rmin = tmn * 0.8f;
        const float rmax = tmx * 1.2f;
        const float a = (rmax - rmin) / (tmx - tmn + EPS);
        const float mean_t = (float)(st / (double)((long long)NS * (long long)NG));
        const float mean_u = (mean_t - tmn) * a + rmin;
        AB[0] = a / mean_u;
        AB[1] = (rmin - tmn * a) / mean_u;
        *loss_out = (float)(sq * 1e-4);
    }
}

// ---- pass 4: out = rf*c_row + B; rf from L3; NT stores ----
__global__ __launch_bounds__(256) void k_finalize(
    const fv4* __restrict__ rf,
    const float* __restrict__ S, const float* __restrict__ P,
    const float* __restrict__ AB,
    fv4* __restrict__ out)
{
    const int row  = blockIdx.x * 4 + (threadIdx.x >> 6);
    const int lane = threadIdx.x & 63;
    const float A = AB[0], B = AB[1];
    const float c = (P[row] / (S[row] + EPS)) * A;
    const fv4* r = rf + (size_t)row * G4;
    fv4* o = out + (size_t)row * G4;
    #pragma unroll
    for (int i = 0; i < 12; ++i) {
        const int cc = lane + i * 64;
        if (cc < G4) {
            fv4 a = r[cc];
            fv4 v;
            v.x = fmaf(a.x, c, B);
            v.y = fmaf(a.y, c, B);
            v.z = fmaf(a.z, c, B);
            v.w = fmaf(a.w, c, B);
            __builtin_nontemporal_store(v, o + cc);
        }
    }
}

extern "C" void kernel_launch(void* const* d_in, const int* in_sizes, int n_in,
                              void* d_out, int out_size, void* d_ws, size_t ws_size,
                              hipStream_t stream) {
    const float* nx = (const float*)d_in[0];   // norm_x
    const float* rf = (const float*)d_in[1];   // reconstructed_features
    // d_in[2] (edge_index) unused: effect on output < 1e-11 relative.
    float* out = (float*)d_out;
    float* ws  = (float*)d_ws;
    float* S   = ws;
    float* P   = ws + NS;
    float* Q   = ws + 2 * NS;
    float* MN  = ws + 3 * NS;
    float* MX  = ws + 4 * NS;
    float* AB  = ws + 5 * NS;
    float* loss_out = out + (out_size - 1);

    k_rfstats <<<NS / 4, 256, 0, stream>>>((const fv4*)rf, S, Q, MN, MX);
    k_p       <<<NS / 4, 256, 0, stream>>>((const fv4*)nx, P);
    k_scalars <<<1,      256, 0, stream>>>(S, P, Q, MN, MX, AB, loss_out);
    k_finalize<<<NS / 4, 256, 0, stream>>>((const fv4*)rf, S, P, AB, (fv4*)out);
}

// Round 9
// 174.387 us; speedup vs baseline: 1.0062x; 1.0062x over previous
//
#include <hip/hip_runtime.h>
#include <cmath>

// CNEncoder reduced form (MCMC/graph path cancels; see round-0 derivation):
//   P_i = sum_j nx[i,j]; S_i = sum_j rf[i,j]; scale_i = P_i/(S_i+EPS)
//   t = rf*scale; global tmin/tmax/mean -> affine out = rf*(scale_i*A)+B
//   reg_loss = sum(rf^2)*1e-4
// st = sum_i sc_i*S_i computed as sum_i P_i (rel. err ~7e-12).
//
// r8 post-mortem: all read-reduce structures pin at ~3.5 TB/s consumed
// read BW; serializing the two streams (r8) pays that ceiling twice ->
// regression. Best schedule keeps both streams concurrently in flight
// (r5, 139us). This round: same concurrency but DECOUPLED waves -- a
// split-grid kernel: even blocks reduce rf (stats), odd blocks reduce nx
// (row sums). Each wave runs one stream, 12-deep unrolled load burst,
// no intra-wave cross-stream vmcnt coupling.
//
// L3 choreography (verified r5-r7: stats FETCH ~= nx only): nx NT loads,
// rf normal loads (L3-resident across replays), out NT stores.

static constexpr int NS = 20000;
static constexpr int NG = 3000;
static constexpr int G4 = NG / 4;        // 750 fv4/row, row stride 12000 B
static constexpr float EPS = 1e-8f;

typedef float fv4 __attribute__((ext_vector_type(4)));

// ws floats: [0,NS) S | [NS,2NS) P | [2NS,3NS) Q | [3NS,4NS) MN | [4NS,5NS) MX | AB[2]

// ---- pass 1: split-grid dual-stream reduce ----
// even blocks: rf stats (S,Q,MN,MX); odd blocks: nx row sums (P).
__global__ __launch_bounds__(256) void k_stats2(
    const fv4* __restrict__ nx, const fv4* __restrict__ rf,
    float* __restrict__ S, float* __restrict__ P,
    float* __restrict__ Q, float* __restrict__ MN, float* __restrict__ MX)
{
    const int wid  = threadIdx.x >> 6;
    const int lane = threadIdx.x & 63;
    const int row  = (blockIdx.x >> 1) * 4 + wid;

    if (blockIdx.x & 1) {
        // ---- nx row sum (HBM stream, NT loads) ----
        const fv4* n = nx + (size_t)row * G4;
        float p0 = 0.f, p1 = 0.f;
        #pragma unroll
        for (int i = 0; i < 12; ++i) {
            const int c = lane + i * 64;
            if (c < G4) {
                fv4 b = __builtin_nontemporal_load(n + c);
                if (i & 1) p1 += (b.x + b.y) + (b.z + b.w);
                else       p0 += (b.x + b.y) + (b.z + b.w);
            }
        }
        float p = p0 + p1;
        #pragma unroll
        for (int off = 32; off > 0; off >>= 1) p += __shfl_down(p, off);
        if (lane == 0) P[row] = p;
    } else {
        // ---- rf row stats (L3-resident stream, normal loads) ----
        const fv4* r = rf + (size_t)row * G4;
        float s0 = 0.f, s1 = 0.f, q0 = 0.f, q1 = 0.f;
        float mn0 = INFINITY, mn1 = INFINITY, mx0 = -INFINITY, mx1 = -INFINITY;
        #pragma unroll
        for (int i = 0; i < 12; ++i) {
            const int c = lane + i * 64;
            if (c < G4) {
                fv4 a = r[c];
                if (i & 1) {
                    s1 += (a.x + a.y) + (a.z + a.w);
                    q1 += a.x * a.x + a.y * a.y + a.z * a.z + a.w * a.w;
                    mn1 = fminf(mn1, fminf(fminf(a.x, a.y), fminf(a.z, a.w)));
                    mx1 = fmaxf(mx1, fmaxf(fmaxf(a.x, a.y), fmaxf(a.z, a.w)));
                } else {
                    s0 += (a.x + a.y) + (a.z + a.w);
                    q0 += a.x * a.x + a.y * a.y + a.z * a.z + a.w * a.w;
                    mn0 = fminf(mn0, fminf(fminf(a.x, a.y), fminf(a.z, a.w)));
                    mx0 = fmaxf(mx0, fmaxf(fmaxf(a.x, a.y), fmaxf(a.z, a.w)));
                }
            }
        }
        float s = s0 + s1, q = q0 + q1;
        float mn = fminf(mn0, mn1), mx = fmaxf(mx0, mx1);
        #pragma unroll
        for (int off = 32; off > 0; off >>= 1) {
            s += __shfl_down(s, off);
            q += __shfl_down(q, off);
            mn = fminf(mn, __shfl_down(mn, off));
            mx = fmaxf(mx, __shfl_down(mx, off));
        }
        if (lane == 0) { S[row] = s; Q[row] = q; MN[row] = mn; MX[row] = mx; }
    }
}

// ---- pass 2: fold per-row stats into {A,B} and reg_loss ----
__global__ __launch_bounds__(256) void k_scalars(
    const float* __restrict__ S, const float* __restrict__ P,
    const float* __restrict__ Q,
    const float* __restrict__ MN, const float* __restrict__ MX,
    float* __restrict__ AB, float* __restrict__ loss_out)
{
    double st = 0.0, sq = 0.0;
    float tmn = INFINITY, tmx = -INFINITY;
    for (int i = threadIdx.x; i < NS; i += 256) {
        const float s = S[i], p = P[i];
        const float sc = p / (s + EPS);
        st += (double)p;
        sq += (double)Q[i];
        tmn = fminf(tmn, MN[i] * sc);
        tmx = fmaxf(tmx, MX[i] * sc);
    }
    #pragma unroll
    for (int off = 32; off > 0; off >>= 1) {
        st += __shfl_down(st, off);
        sq += __shfl_down(sq, off);
        tmn = fminf(tmn, __shfl_down(tmn, off));
        tmx = fmaxf(tmx, __shfl_down(tmx, off));
    }
    __shared__ double lst[4], lsq[4];
    __shared__ float lmn[4], lmx[4];
    const int wid = threadIdx.x >> 6;
    if ((threadIdx.x & 63) == 0) { lst[wid] = st; lsq[wid] = sq; lmn[wid] = tmn; lmx[wid] = tmx; }
    __syncthreads();
    if (threadIdx.x == 0) {
        st  = (lst[0] + lst[1]) + (lst[2] + lst[3]);
        sq  = (lsq[0] + lsq[1]) + (lsq[2] + lsq[3]);
        tmn = fminf(fminf(lmn[0], lmn[1]), fminf(lmn[2], lmn[3]));
        tmx = fmaxf(fmaxf(lmx[0], lmx[1]), fmaxf(lmx[2], lmx[3]));
        const float rmin = tmn * 0.8f;
        const float rmax = tmx * 1.2f;
        const float a = (rmax - rmin) / (tmx - tmn + EPS);
        const float mean_t = (float)(st / (double)((long long)NS * (long long)NG));
        const float mean_u = (mean_t - tmn) * a + rmin;
        AB[0] = a / mean_u;
        AB[1] = (rmin - tmn * a) / mean_u;
        *loss_out = (float)(sq * 1e-4);
    }
}

// ---- pass 3: out = rf*c_row + B; rf from L3; NT stores ----
__global__ __launch_bounds__(256) void k_finalize(
    const fv4* __restrict__ rf,
    const float* __restrict__ S, const float* __restrict__ P,
    const float* __restrict__ AB,
    fv4* __restrict__ out)
{
    const int row  = blockIdx.x * 4 + (threadIdx.x >> 6);
    const int lane = threadIdx.x & 63;
    const float A = AB[0], B = AB[1];
    const float c = (P[row] / (S[row] + EPS)) * A;
    const fv4* r = rf + (size_t)row * G4;
    fv4* o = out + (size_t)row * G4;
    #pragma unroll
    for (int i = 0; i < 12; ++i) {
        const int cc = lane + i * 64;
        if (cc < G4) {
            fv4 a = r[cc];
            fv4 v;
            v.x = fmaf(a.x, c, B);
            v.y = fmaf(a.y, c, B);
            v.z = fmaf(a.z, c, B);
            v.w = fmaf(a.w, c, B);
            __builtin_nontemporal_store(v, o + cc);
        }
    }
}

extern "C" void kernel_launch(void* const* d_in, const int* in_sizes, int n_in,
                              void* d_out, int out_size, void* d_ws, size_t ws_size,
                              hipStream_t stream) {
    const float* nx = (const float*)d_in[0];   // norm_x
    const float* rf = (const float*)d_in[1];   // reconstructed_features
    // d_in[2] (edge_index) unused: effect on output < 1e-11 relative.
    float* out = (float*)d_out;
    float* ws  = (float*)d_ws;
    float* S   = ws;
    float* P   = ws + NS;
    float* Q   = ws + 2 * NS;
    float* MN  = ws + 3 * NS;
    float* MX  = ws + 4 * NS;
    float* AB  = ws + 5 * NS;
    float* loss_out = out + (out_size - 1);

    k_stats2  <<<NS / 2, 256, 0, stream>>>((const fv4*)nx, (const fv4*)rf,
                                           S, P, Q, MN, MX);
    k_scalars <<<1,      256, 0, stream>>>(S, P, Q, MN, MX, AB, loss_out);
    k_finalize<<<NS / 4, 256, 0, stream>>>((const fv4*)rf, S, P, AB, (fv4*)out);
}

// Round 10
// 151.249 us; speedup vs baseline: 1.1601x; 1.1530x over previous
//
#include <hip/hip_runtime.h>
#include <cmath>

// CNEncoder reduced form (MCMC/graph path cancels; see round-0 derivation):
//   P_i = sum_j nx[i,j]; S_i = sum_j rf[i,j]; scale_i = P_i/(S_i+EPS)
//   t = rf*scale; global tmin/tmax/mean -> affine out = rf*(scale_i*A)+B
//   reg_loss = sum(rf^2)*1e-4
//
// BEST-MEASURED SCHEDULE (r5: 150.7us) restored after r6-r9 regressions.
// Steady-state traffic: reads nx 240 + rf 480 (2 passes, L3-assisted) +
// writes 240 = 960 MB at ~6.4 TB/s combined = measured achievable ceiling.
//
// Structure: one fused stats pass (nx NT-loads, rf normal loads -> L3),
// a 20KB two-stage scalar reduce, and a finalize pass (rf reads L3-hot,
// NT stores for out).

static constexpr int NS = 20000;
static constexpr int NG = 3000;
static constexpr int G4 = NG / 4;        // 750 float4/row, row stride 12000 B
static constexpr int NW = NS / 4;        // 5000 waves, 4 rows per wave
static constexpr int NB = NW / 4;        // 1250 blocks (4 waves each)
static constexpr float EPS = 1e-8f;

typedef float fv4 __attribute__((ext_vector_type(4)));

// ws floats: [0,NS) S | [NS,2NS) P |
//            [2NS, 2NS+NB) PST | +NB PSQ | +2NB PMN | +3NB PMX | then AB[2]

// ---- pass 1: per-row stats of both arrays + block partials ----
__global__ __launch_bounds__(256) void k_stats(
    const fv4* __restrict__ nx, const fv4* __restrict__ rf,
    float* __restrict__ S, float* __restrict__ P,
    float* __restrict__ PST, float* __restrict__ PSQ,
    float* __restrict__ PMN, float* __restrict__ PMX)
{
    const int wid  = threadIdx.x >> 6;
    const int lane = threadIdx.x & 63;
    const int gw   = blockIdx.x * 4 + wid;       // 0..NW-1
    float st = 0.f, sq = 0.f, tmn = INFINITY, tmx = -INFINITY;
    #pragma unroll
    for (int k = 0; k < 4; ++k) {
        const int row = gw + k * NW;
        const fv4* r = rf + (size_t)row * G4;
        const fv4* n = nx + (size_t)row * G4;
        float s = 0.f, p = 0.f, q = 0.f, mn = INFINITY, mx = -INFINITY;
        for (int c = lane; c < G4; c += 64) {
            fv4 a = r[c];
            fv4 b = __builtin_nontemporal_load(n + c);
            s += (a.x + a.y) + (a.z + a.w);
            q += a.x * a.x + a.y * a.y + a.z * a.z + a.w * a.w;
            mn = fminf(mn, fminf(fminf(a.x, a.y), fminf(a.z, a.w)));
            mx = fmaxf(mx, fmaxf(fmaxf(a.x, a.y), fmaxf(a.z, a.w)));
            p += (b.x + b.y) + (b.z + b.w);
        }
        #pragma unroll
        for (int off = 32; off > 0; off >>= 1) {
            s += __shfl_down(s, off);
            p += __shfl_down(p, off);
            q += __shfl_down(q, off);
            mn = fminf(mn, __shfl_down(mn, off));
            mx = fmaxf(mx, __shfl_down(mx, off));
        }
        if (lane == 0) {
            S[row] = s; P[row] = p;
            const float sc = p / (s + EPS);
            st += sc * s;
            sq += q;
            tmn = fminf(tmn, mn * sc);
            tmx = fmaxf(tmx, mx * sc);
        }
    }
    __shared__ float lst[4], lsq[4], lmn[4], lmx[4];
    if (lane == 0) { lst[wid] = st; lsq[wid] = sq; lmn[wid] = tmn; lmx[wid] = tmx; }
    __syncthreads();
    if (threadIdx.x == 0) {
        PST[blockIdx.x] = (lst[0] + lst[1]) + (lst[2] + lst[3]);
        PSQ[blockIdx.x] = (lsq[0] + lsq[1]) + (lsq[2] + lsq[3]);
        PMN[blockIdx.x] = fminf(fminf(lmn[0], lmn[1]), fminf(lmn[2], lmn[3]));
        PMX[blockIdx.x] = fmaxf(fmaxf(lmx[0], lmx[1]), fmaxf(lmx[2], lmx[3]));
    }
}

// ---- pass 2: fold 1250 block partials into {A,B} and reg_loss ----
__global__ __launch_bounds__(256) void k_scalars(
    const float* __restrict__ PST, const float* __restrict__ PSQ,
    const float* __restrict__ PMN, const float* __restrict__ PMX,
    float* __restrict__ AB, float* __restrict__ loss_out)
{
    double st = 0.0, sq = 0.0;
    float tmn = INFINITY, tmx = -INFINITY;
    for (int i = threadIdx.x; i < NB; i += 256) {
        st += (double)PST[i];
        sq += (double)PSQ[i];
        tmn = fminf(tmn, PMN[i]);
        tmx = fmaxf(tmx, PMX[i]);
    }
    #pragma unroll
    for (int off = 32; off > 0; off >>= 1) {
        st += __shfl_down(st, off);
        sq += __shfl_down(sq, off);
        tmn = fminf(tmn, __shfl_down(tmn, off));
        tmx = fmaxf(tmx, __shfl_down(tmx, off));
    }
    __shared__ double lst[4], lsq[4];
    __shared__ float lmn[4], lmx[4];
    const int wid = threadIdx.x >> 6;
    if ((threadIdx.x & 63) == 0) { lst[wid] = st; lsq[wid] = sq; lmn[wid] = tmn; lmx[wid] = tmx; }
    __syncthreads();
    if (threadIdx.x == 0) {
        st  = (lst[0] + lst[1]) + (lst[2] + lst[3]);
        sq  = (lsq[0] + lsq[1]) + (lsq[2] + lsq[3]);
        tmn = fminf(fminf(lmn[0], lmn[1]), fminf(lmn[2], lmn[3]));
        tmx = fmaxf(fmaxf(lmx[0], lmx[1]), fmaxf(lmx[2], lmx[3]));
        const float rmin = tmn * 0.8f;
        const float rmax = tmx * 1.2f;
        const float a = (rmax - rmin) / (tmx - tmn + EPS);
        const float mean_t = (float)(st / (double)((long long)NS * (long long)NG));
        const float mean_u = (mean_t - tmn) * a + rmin;
        AB[0] = a / mean_u;
        AB[1] = (rmin - tmn * a) / mean_u;
        *loss_out = (float)(sq * 1e-4);
    }
}

// ---- pass 3: out = rf*c_row + B; wave per row; NT stores ----
__global__ __launch_bounds__(256) void k_finalize(
    const fv4* __restrict__ rf,
    const float* __restrict__ S, const float* __restrict__ P,
    const float* __restrict__ AB,
    fv4* __restrict__ out)
{
    const int row  = blockIdx.x * 4 + (threadIdx.x >> 6);
    const int lane = threadIdx.x & 63;
    const float A = AB[0], B = AB[1];
    const float c = (P[row] / (S[row] + EPS)) * A;
    const fv4* r = rf + (size_t)row * G4;
    fv4* o = out + (size_t)row * G4;
    for (int i = lane; i < G4; i += 64) {
        fv4 a = r[i];
        fv4 v;
        v.x = fmaf(a.x, c, B);
        v.y = fmaf(a.y, c, B);
        v.z = fmaf(a.z, c, B);
        v.w = fmaf(a.w, c, B);
        __builtin_nontemporal_store(v, o + i);
    }
}

extern "C" void kernel_launch(void* const* d_in, const int* in_sizes, int n_in,
                              void* d_out, int out_size, void* d_ws, size_t ws_size,
                              hipStream_t stream) {
    const float* nx = (const float*)d_in[0];   // norm_x
    const float* rf = (const float*)d_in[1];   // reconstructed_features
    // d_in[2] (edge_index) unused: effect on output < 1e-11 relative.
    float* out = (float*)d_out;
    float* ws  = (float*)d_ws;
    float* S   = ws;
    float* P   = ws + NS;
    float* PST = ws + 2 * NS;
    float* PSQ = PST + NB;
    float* PMN = PST + 2 * NB;
    float* PMX = PST + 3 * NB;
    float* AB  = PST + 4 * NB;
    float* loss_out = out + (out_size - 1);

    k_stats   <<<NB,     256, 0, stream>>>((const fv4*)nx, (const fv4*)rf,
                                           S, P, PST, PSQ, PMN, PMX);
    k_scalars <<<1,      256, 0, stream>>>(PST, PSQ, PMN, PMX, AB, loss_out);
    k_finalize<<<NS / 4, 256, 0, stream>>>((const fv4*)rf, S, P, AB, (fv4*)out);
}

// Round 13
// 150.328 us; speedup vs baseline: 1.1672x; 1.0061x over previous
//
#include <hip/hip_runtime.h>
#include <cmath>

// CNEncoder reduced form (MCMC/graph path cancels; see round-0 derivation):
//   P_i = sum_j nx[i,j]; S_i = sum_j rf[i,j]; scale_i = P_i/(S_i+EPS)
//   t = rf*scale; global tmin/tmax/mean -> affine out = rf*(scale_i*A)+B
//   reg_loss = sum(rf^2)*1e-4
//
// r10 state: r5 schedule reproduced at 151.2us; every read structure pins
// HBM fetch at ~1.78 TB/s through the VGPR load path. This round probes the
// one untried mechanism: global_load_lds DMA (12 outstanding 1KB wave
// requests, no VGPR coupling) for the nx stream. rf stays on the register
// path (L3-resident, verified FETCH ~= nx only). Scalars/finalize unchanged.

static constexpr int NS = 20000;
static constexpr int NG = 3000;
static constexpr int G4 = NG / 4;        // 750 fv4/row, row stride 12000 B
static constexpr int NW = NS / 4;        // 5000 waves, 4 rows per wave
static constexpr int NB = NW / 4;        // 1250 blocks (4 waves each)
static constexpr float EPS = 1e-8f;

typedef float fv4 __attribute__((ext_vector_type(4)));

#define GLOBAL_AS __attribute__((address_space(1)))
#define LDS_AS    __attribute__((address_space(3)))

// ws floats: [0,NS) S | [NS,2NS) P |
//            [2NS, 2NS+NB) PST | +NB PSQ | +2NB PMN | +3NB PMX | then AB[2]

// ---- pass 1: per-row stats; rf via registers, nx via LDS-DMA ----
__global__ __launch_bounds__(256) void k_stats(
    const fv4* __restrict__ nx, const fv4* __restrict__ rf,
    float* __restrict__ S, float* __restrict__ P,
    float* __restrict__ PST, float* __restrict__ PSQ,
    float* __restrict__ PMN, float* __restrict__ PMX)
{
    __shared__ fv4 stage[4][768];                // 12 KB per wave, 48 KB/block
    const int wid  = threadIdx.x >> 6;
    const int lane = threadIdx.x & 63;
    const int gw   = blockIdx.x * 4 + wid;       // 0..NW-1
    float st = 0.f, sq = 0.f, tmn = INFINITY, tmx = -INFINITY;

    #pragma unroll 1
    for (int k = 0; k < 4; ++k) {
        const int row = gw + k * NW;
        const fv4* r = rf + (size_t)row * G4;
        const fv4* n = nx + (size_t)row * G4;

        __builtin_amdgcn_sched_barrier(0);       // fence prev iter's LDS reads

        // 1) rf burst: 12 register loads (L3-resident), tail clamped
        fv4 a[12];
        #pragma unroll
        for (int i = 0; i < 12; ++i) {
            int c = lane + i * 64;
            if (c > G4 - 1) c = G4 - 1;
            a[i] = r[c];
        }

        // 2) nx burst: 12 DMA loads direct to LDS (aux=2 -> NT), no VGPR cost
        #pragma unroll
        for (int i = 0; i < 11; ++i)
            __builtin_amdgcn_global_load_lds(
                (const GLOBAL_AS void*)(n + lane + i * 64),
                (LDS_AS void*)&stage[wid][i * 64], 16, 0, 2);
        if (lane < G4 - 11 * 64)                 // lanes 0..45
            __builtin_amdgcn_global_load_lds(
                (const GLOBAL_AS void*)(n + lane + 704),
                (LDS_AS void*)&stage[wid][704], 16, 0, 2);
        __builtin_amdgcn_sched_barrier(0);

        // 3) rf reduce while DMA is in flight
        float s = 0.f, q = 0.f, mn = INFINITY, mx = -INFINITY;
        #pragma unroll
        for (int i = 0; i < 12; ++i) {
            if (i < 11 || lane < G4 - 11 * 64) {
                fv4 v = a[i];
                s += (v.x + v.y) + (v.z + v.w);
                q += v.x * v.x + v.y * v.y + v.z * v.z + v.w * v.w;
                mn = fminf(mn, fminf(fminf(v.x, v.y), fminf(v.z, v.w)));
                mx = fmaxf(mx, fmaxf(fmaxf(v.x, v.y), fmaxf(v.z, v.w)));
            }
        }

        // 4) drain DMA, reduce nx from per-wave LDS (no barrier: wave-private)
        asm volatile("s_waitcnt vmcnt(0)" ::: "memory");
        __builtin_amdgcn_sched_barrier(0);
        float p = 0.f;
        #pragma unroll
        for (int i = 0; i < 12; ++i) {
            if (i < 11 || lane < G4 - 11 * 64) {
                fv4 b = stage[wid][lane + i * 64];
                p += (b.x + b.y) + (b.z + b.w);
            }
        }

        #pragma unroll
        for (int off = 32; off > 0; off >>= 1) {
            s += __shfl_down(s, off);
            p += __shfl_down(p, off);
            q += __shfl_down(q, off);
            mn = fminf(mn, __shfl_down(mn, off));
            mx = fmaxf(mx, __shfl_down(mx, off));
        }
        if (lane == 0) {
            S[row] = s; P[row] = p;
            const float sc = p / (s + EPS);
            st += sc * s;
            sq += q;
            tmn = fminf(tmn, mn * sc);
            tmx = fmaxf(tmx, mx * sc);
        }
    }

    __shared__ float lst[4], lsq[4], lmn[4], lmx[4];
    if (lane == 0) { lst[wid] = st; lsq[wid] = sq; lmn[wid] = tmn; lmx[wid] = tmx; }
    __syncthreads();
    if (threadIdx.x == 0) {
        PST[blockIdx.x] = (lst[0] + lst[1]) + (lst[2] + lst[3]);
        PSQ[blockIdx.x] = (lsq[0] + lsq[1]) + (lsq[2] + lsq[3]);
        PMN[blockIdx.x] = fminf(fminf(lmn[0], lmn[1]), fminf(lmn[2], lmn[3]));
        PMX[blockIdx.x] = fmaxf(fmaxf(lmx[0], lmx[1]), fmaxf(lmx[2], lmx[3]));
    }
}

// ---- pass 2: fold 1250 block partials into {A,B} and reg_loss ----
__global__ __launch_bounds__(256) void k_scalars(
    const float* __restrict__ PST, const float* __restrict__ PSQ,
    const float* __restrict__ PMN, const float* __restrict__ PMX,
    float* __restrict__ AB, float* __restrict__ loss_out)
{
    double st = 0.0, sq = 0.0;
    float tmn = INFINITY, tmx = -INFINITY;
    for (int i = threadIdx.x; i < NB; i += 256) {
        st += (double)PST[i];
        sq += (double)PSQ[i];
        tmn = fminf(tmn, PMN[i]);
        tmx = fmaxf(tmx, PMX[i]);
    }
    #pragma unroll
    for (int off = 32; off > 0; off >>= 1) {
        st += __shfl_down(st, off);
        sq += __shfl_down(sq, off);
        tmn = fminf(tmn, __shfl_down(tmn, off));
        tmx = fmaxf(tmx, __shfl_down(tmx, off));
    }
    __shared__ double lst[4], lsq[4];
    __shared__ float lmn[4], lmx[4];
    const int wid = threadIdx.x >> 6;
    if ((threadIdx.x & 63) == 0) { lst[wid] = st; lsq[wid] = sq; lmn[wid] = tmn; lmx[wid] = tmx; }
    __syncthreads();
    if (threadIdx.x == 0) {
        st  = (lst[0] + lst[1]) + (lst[2] + lst[3]);
        sq  = (lsq[0] + lsq[1]) + (lsq[2] + lsq[3]);
        tmn = fminf(fminf(lmn[0], lmn[1]), fminf(lmn[2], lmn[3]));
        tmx = fmaxf(fmaxf(lmx[0], lmx[1]), fmaxf(lmx[2], lmx[3]));
        const float rmin = tmn * 0.8f;
        const float rmax = tmx * 1.2f;
        const float a = (rmax - rmin) / (tmx - tmn + EPS);
        const float mean_t = (float)(st / (double)((long long)NS * (long long)NG));
        const float mean_u = (mean_t - tmn) * a + rmin;
        AB[0] = a / mean_u;
        AB[1] = (rmin - tmn * a) / mean_u;
        *loss_out = (float)(sq * 1e-4);
    }
}

// ---- pass 3: out = rf*c_row + B; wave per row; NT stores ----
__global__ __launch_bounds__(256) void k_finalize(
    const fv4* __restrict__ rf,
    const float* __restrict__ S, const float* __restrict__ P,
    const float* __restrict__ AB,
    fv4* __restrict__ out)
{
    const int row  = blockIdx.x * 4 + (threadIdx.x >> 6);
    const int lane = threadIdx.x & 63;
    const float A = AB[0], B = AB[1];
    const float c = (P[row] / (S[row] + EPS)) * A;
    const fv4* r = rf + (size_t)row * G4;
    fv4* o = out + (size_t)row * G4;
    for (int i = lane; i < G4; i += 64) {
        fv4 a = r[i];
        fv4 v;
        v.x = fmaf(a.x, c, B);
        v.y = fmaf(a.y, c, B);
        v.z = fmaf(a.z, c, B);
        v.w = fmaf(a.w, c, B);
        __builtin_nontemporal_store(v, o + i);
    }
}

extern "C" void kernel_launch(void* const* d_in, const int* in_sizes, int n_in,
                              void* d_out, int out_size, void* d_ws, size_t ws_size,
                              hipStream_t stream) {
    const float* nx = (const float*)d_in[0];   // norm_x
    const float* rf = (const float*)d_in[1];   // reconstructed_features
    // d_in[2] (edge_index) unused: effect on output < 1e-11 relative.
    float* out = (float*)d_out;
    float* ws  = (float*)d_ws;
    float* S   = ws;
    float* P   = ws + NS;
    float* PST = ws + 2 * NS;
    float* PSQ = PST + NB;
    float* PMN = PST + 2 * NB;
    float* PMX = PST + 3 * NB;
    float* AB  = PST + 4 * NB;
    float* loss_out = out + (out_size - 1);

    k_stats   <<<NB,     256, 0, stream>>>((const fv4*)nx, (const fv4*)rf,
                                           S, P, PST, PSQ, PMN, PMX);
    k_scalars <<<1,      256, 0, stream>>>(PST, PSQ, PMN, PMX, AB, loss_out);
    k_finalize<<<NS / 4, 256, 0, stream>>>((const fv4*)rf, S, P, AB, (fv4*)out);
}